// Round 9
// baseline (246.282 us; speedup 1.0000x reference)
//
#include <hip/hip_runtime.h>
#include <hip/hip_fp16.h>
#include <stdint.h>

#define IN_DIM 512
#define NT 64
#define AH 128
#define NCLS 10
#define BN_EPS_C 1e-5f
#define SHRINK 0.3f
#define HSTRIDE 66   // f16 decision plane stride: 66 h16 = 33 dw, coprime mod 32
#define HPLANE 8448  // 128 * 66 h16 per tree plane

typedef __bf16 bf16x8 __attribute__((ext_vector_type(8)));
typedef float f32x4 __attribute__((ext_vector_type(4)));
typedef unsigned int u32x4 __attribute__((ext_vector_type(4)));

__device__ __forceinline__ unsigned short f2bf(float f) {
  unsigned u = __builtin_bit_cast(unsigned, f);
  u += 0x7fffu + ((u >> 16) & 1u);   // RNE; inputs are NaN-free after NaN-zeroing
  return (unsigned short)(u >> 16);
}

__device__ __forceinline__ float bflo(unsigned w) {
  return __builtin_bit_cast(float, w << 16);
}
__device__ __forceinline__ float bfhi(unsigned w) {
  return __builtin_bit_cast(float, w & 0xffff0000u);
}

__device__ __forceinline__ void gload_lds16(const void* g, void* l) {
  __builtin_amdgcn_global_load_lds(
      (const __attribute__((address_space(1))) void*)g,
      (__attribute__((address_space(3))) void*)l, 16, 0, 0);
}

// read one 16B MFMA fragment from a swizzled [rows][64] bf16 LDS tile (BK=64)
// row stride 128B == 0 mod 32 banks; 8-deep XOR -> 16-row frag read is 2-way
// (free). R2 lesson: BK=32 (64B stride, 4-deep XOR) is 4-way -> 5x conflicts.
__device__ __forceinline__ bf16x8 frag_ld(const char* lds, int r, int q) {
  return *reinterpret_cast<const bf16x8*>(lds + r * 128 + ((q ^ (r & 7)) * 16));
}

// stage one 128x64 A tile + 128x64 B tile (BK=64, 16KB each)
__device__ __forceinline__ void stage_trees(const unsigned short* Ak,
                                            const unsigned short* Bk,
                                            char* As, char* Bs,
                                            int wid, int sub, int cpos) {
#pragma unroll
  for (int i = 0; i < 4; i++) {
    int seg = wid * 4 + i;
    int r = seg * 8 + sub;
    int cg = cpos ^ (r & 7);
    gload_lds16(Ak + r * 512 + cg * 8, As + seg * 1024);
    gload_lds16(Bk + r * 512 + cg * 8, Bs + seg * 1024);
  }
}

// ------ prep: tree_w->bf16(pad), w1->w1t, x->xc+flags (R7 config) ----------
// R6 lesson: NO device-scope fences in hot kernels. Cross-kernel stream
// order is the cheap sync. x-conversion here runs at full HBM width.
__global__ void __launch_bounds__(256) k_prep(
    const float* __restrict__ tw, unsigned short* __restrict__ twb,
    const float* __restrict__ w1, unsigned short* __restrict__ w1t,
    const float* __restrict__ x, unsigned short* __restrict__ xc,
    unsigned char* __restrict__ flags) {
  int b = blockIdx.x;
  if (b < 1024) {
    int tid = b * 256 + threadIdx.x;  // 262144
    int o = tid * 8;
    int k = o & 511;
    int nt = o >> 9;
    int node = nt & 63, t = nt >> 6;
    union { unsigned short s[8]; u32x4 u; } pk;
    if (node < 63) {
      const float* p = tw + ((t * 63 + node) * 512 + k);
      float4 a = *(const float4*)p, bb = *(const float4*)(p + 4);
      float v[8] = {a.x, a.y, a.z, a.w, bb.x, bb.y, bb.z, bb.w};
#pragma unroll
      for (int i = 0; i < 8; i++) pk.s[i] = f2bf(v[i]);
    } else {
#pragma unroll
      for (int i = 0; i < 8; i++) pk.s[i] = 0;
    }
    *reinterpret_cast<u32x4*>(twb + o) = pk.u;
  } else if (b < 1280) {
    int tid = (b - 1024) * 256 + threadIdx.x;  // 65536
    int k = tid & 511, n = tid >> 9;
    w1t[n * 512 + k] = f2bf(w1[k * 128 + n]);
  } else {
    // x -> xc + flags: one wave per row
    int tid = (b - 1280) * 256 + threadIdx.x;  // 0..1048575
    int row = tid >> 6;
    int lane = threadIdx.x & 63;
    const float* px = x + (size_t)row * 512 + lane * 8;
    float4 a = *(const float4*)px;
    float4 bb = *(const float4*)(px + 4);
    float v[8] = {a.x, a.y, a.z, a.w, bb.x, bb.y, bb.z, bb.w};
    bool nan_any = false;
    union { unsigned short s[8]; u32x4 u; } pk;
#pragma unroll
    for (int j = 0; j < 8; j++) {
      bool n = (v[j] != v[j]);
      nan_any |= n;
      pk.s[j] = f2bf(n ? 0.f : v[j]);
    }
    *reinterpret_cast<u32x4*>(xc + (size_t)row * 512 + lane * 8) = pk.u;
    unsigned long long bal = __ballot(nan_any);
    if (lane == 0) flags[row] = bal ? 1 : 0;
  }
}

// ---------------- attention: 32-row tiles, 512 blocks = 2/CU (R8 config) ---
// R19: + s_setprio(1) around the MFMA cluster (T5). With 2 blocks/CU at
// drifting phases, MFMA-phase waves win issue arbitration over the other
// block's staging waves (m191 mechanism: independent blocks, not lockstep).
__global__ void __launch_bounds__(256) k_attn(
    const unsigned short* __restrict__ xc,
    const unsigned short* __restrict__ w1t,
    const float* __restrict__ b1, const float* __restrict__ gam,
    const float* __restrict__ bet, const float* __restrict__ mu,
    const float* __restrict__ var, const float* __restrict__ w2,
    const float* __restrict__ b2, const float* __restrict__ rw,
    float* __restrict__ wbt) {
  __shared__ __align__(16) char smem[46592];
  char* As = smem;                                        // 32x64 bf16 = 4096
  char* Bs = smem + 4096;                                 // 128x64 bf16 = 16384
  unsigned short* hb  = (unsigned short*)(smem + 20480);  // [32][136] bf16 = 8704
  unsigned short* w2s = (unsigned short*)(smem + 29184);  // [64][136] bf16 = 17408
  int lane = threadIdx.x & 63, wid = threadIdx.x >> 6;
  int bm0 = blockIdx.x * 32;
  int m = lane & 15, q = lane >> 4;
  int sub = lane >> 3, cpos = lane & 7;
  int wr = wid & 1, wc = wid >> 1;   // wave grid 2x2 over 32 rows x 128 cols

  for (int i = threadIdx.x; i < AH * NT; i += 256) {
    int k = i >> 6, n = i & 63;
    w2s[n * 136 + k] = f2bf(w2[i]);
  }
  __syncthreads();  // w2s visible

  f32x4 acc[4];
#pragma unroll
  for (int j = 0; j < 4; j++) acc[j] = f32x4{0.f, 0.f, 0.f, 0.f};
  const unsigned short* Ag = xc + (size_t)bm0 * 512;

  for (int ko = 0; ko < 8; ++ko) {
    const unsigned short* Ak = Ag + ko * 64;
    const unsigned short* Bk = w1t + ko * 64;
    {  // A: 4 segs (32 rows), one per wave
      int seg = wid;
      int r = seg * 8 + sub;
      int cg = cpos ^ (r & 7);
      gload_lds16(Ak + r * 512 + cg * 8, As + seg * 1024);
    }
#pragma unroll
    for (int i = 0; i < 4; i++) {  // B: 16 segs, 4 per wave
      int seg = wid * 4 + i;
      int r = seg * 8 + sub;
      int cg = cpos ^ (r & 7);
      gload_lds16(Bk + r * 512 + cg * 8, Bs + seg * 1024);
    }
    __syncthreads();
    __builtin_amdgcn_s_setprio(1);
#pragma unroll
    for (int ks = 0; ks < 2; ++ks) {
      bf16x8 af = frag_ld(As, wr * 16 + m, ks * 4 + q);
#pragma unroll
      for (int ni = 0; ni < 4; ni++) {
        bf16x8 bfr = frag_ld(Bs, wc * 64 + ni * 16 + m, ks * 4 + q);
        acc[ni] = __builtin_amdgcn_mfma_f32_16x16x32_bf16(af, bfr, acc[ni], 0, 0, 0);
      }
    }
    __builtin_amdgcn_s_setprio(0);
    __syncthreads();
  }

  // BN epilogue: wave (wr,wc) owns rows wr*16..+16, cols wc*64..+64
#pragma unroll
  for (int ni = 0; ni < 4; ni++) {
    int col = wc * 64 + ni * 16 + m;
    float bb = b1[col], ga = gam[col], be = bet[col], mm = mu[col];
    float iv = rsqrtf(var[col] + BN_EPS_C);
#pragma unroll
    for (int r4 = 0; r4 < 4; r4++) {
      int rl = wr * 16 + q * 4 + r4;
      float v = acc[ni][r4] + bb;
      v = fmaxf(v, 0.f);
      v = (v - mm) * iv * ga + be;
      hb[rl * 136 + col] = f2bf(v);
    }
  }
  __syncthreads();

  // GEMM2 + softmax on waves 0-1 (wave w: rows w*16..+16, all 64 trees)
  if (wid < 2) {
    f32x4 acc2[4];
#pragma unroll
    for (int nt = 0; nt < 4; nt++) acc2[nt] = f32x4{0.f, 0.f, 0.f, 0.f};
#pragma unroll
    for (int ks = 0; ks < 4; ++ks) {
      bf16x8 af = *reinterpret_cast<const bf16x8*>(hb + (wid * 16 + m) * 136 + ks * 32 + q * 8);
#pragma unroll
      for (int nt = 0; nt < 4; nt++) {
        bf16x8 bfr = *reinterpret_cast<const bf16x8*>(w2s + (nt * 16 + m) * 136 + ks * 32 + q * 8);
        acc2[nt] = __builtin_amdgcn_mfma_f32_16x16x32_bf16(af, bfr, acc2[nt], 0, 0, 0);
      }
    }

    float b2v[4], cfv[4];
#pragma unroll
    for (int nt = 0; nt < 4; nt++) {
      int col = nt * 16 + m;
      b2v[nt] = b2[col];
      cfv[nt] = SHRINK * rw[col];
    }
#pragma unroll
    for (int reg = 0; reg < 4; ++reg) {
      float s0 = acc2[0][reg] + b2v[0];
      float s1 = acc2[1][reg] + b2v[1];
      float s2 = acc2[2][reg] + b2v[2];
      float s3 = acc2[3][reg] + b2v[3];
      float mx = fmaxf(fmaxf(s0, s1), fmaxf(s2, s3));
#pragma unroll
      for (int o = 1; o < 16; o <<= 1) mx = fmaxf(mx, __shfl_xor(mx, o));
      float e0 = __expf(s0 - mx), e1 = __expf(s1 - mx);
      float e2 = __expf(s2 - mx), e3 = __expf(s3 - mx);
      float sm = e0 + e1 + e2 + e3;
#pragma unroll
      for (int o = 1; o < 16; o <<= 1) sm += __shfl_xor(sm, o);
      float inv = 1.f / sm;
      int row = bm0 + wid * 16 + q * 4 + reg;
      wbt[row * NT + m]      = e0 * inv * cfv[0];
      wbt[row * NT + 16 + m] = e1 * inv * cfv[1];
      wbt[row * NT + 32 + m] = e2 * inv * cfv[2];
      wbt[row * NT + 48 + m] = e3 * inv * cfv[3];
    }
  }
}

// ---------------- main: tree logits + routing + leaf -> per-slice partials ----
// R19: FROZEN R3/R7 structure + s_setprio(1) around MFMA cluster (T5).
// Mechanism: 2 blocks/CU at drifting barrier phases -- MFMA-cluster waves
// preempt the co-resident block's staging waves (m191's independent-block
// case, not m190's lockstep null). If null (128.5 +/- 0.5), T5 is measured
// out and the structure is at its practical plateau.
// Falsified levers: BK=32 (R2), A-reg staging (R4), LDS shrink (R2/R4),
// in-kernel fence finish (R6), fused prep (R5).
__global__ void __launch_bounds__(256) k_trees(
    const unsigned short* __restrict__ xc,   // [16384][512]
    const unsigned short* __restrict__ twb,  // [64*64][512]
    const float* __restrict__ tree_b,        // [64][63]
    const float* __restrict__ tree_temp,     // [64]
    const float* __restrict__ leaf,          // [64][64][10]
    const float* __restrict__ wbt,           // [16384][64]
    const unsigned char* __restrict__ flags, // [16384]
    unsigned short* __restrict__ part) {     // [16384][32][10] bf16
  __shared__ __align__(16) char smem[65536];
  char* A0 = smem;                                  // 128x64 bf16 = 16384
  char* B0 = smem + 16384;
  char* A1 = smem + 32768;
  char* B1 = smem + 49152;
  unsigned short* dh = (unsigned short*)smem;       // 2 planes x 128 x 66 f16 = 33792
  int lane = threadIdx.x & 63, wid = threadIdx.x >> 6;
  int bm0 = blockIdx.y * 128;   // row tile
  int t0 = blockIdx.x * 2;      // tree pair (fast grid dim for L2 sharing)
  int m = lane & 15, q = lane >> 4;
  int sub = lane >> 3, cpos = lane & 7;
  int wr = wid >> 1, wc = wid & 1;   // wave grid 2x2 over 128 rows x 128 cols
  int row_l = threadIdx.x & 127;
  int h = __builtin_amdgcn_readfirstlane((int)(threadIdx.x >> 7));  // wave-uniform half
  int grow = bm0 + row_l;

  f32x4 acc[4][4];
#pragma unroll
  for (int i = 0; i < 4; i++)
#pragma unroll
    for (int j = 0; j < 4; j++) acc[i][j] = f32x4{0.f, 0.f, 0.f, 0.f};

  const unsigned short* Ag = xc + (size_t)bm0 * 512;
  const unsigned short* Bg = twb + (size_t)t0 * 64 * 512;

  stage_trees(Ag, Bg, A0, B0, wid, sub, cpos);
  __syncthreads();  // prologue stage landed (only exposed drain)

#pragma unroll
  for (int ko = 0; ko < 8; ++ko) {
    char* As = (ko & 1) ? A1 : A0;
    char* Bs = (ko & 1) ? B1 : B0;
    if (ko < 7) {  // prefetch next K-tile BEFORE compute
      char* An = (ko & 1) ? A0 : A1;
      char* Bn = (ko & 1) ? B0 : B1;
      stage_trees(Ag + (ko + 1) * 64, Bg + (ko + 1) * 64, An, Bn, wid, sub, cpos);
    }
    __builtin_amdgcn_s_setprio(1);
#pragma unroll
    for (int ks = 0; ks < 2; ++ks) {
      bf16x8 af[4], bfr[4];
#pragma unroll
      for (int mi = 0; mi < 4; mi++) af[mi] = frag_ld(As, wr * 64 + mi * 16 + m, ks * 4 + q);
#pragma unroll
      for (int ni = 0; ni < 4; ni++) bfr[ni] = frag_ld(Bs, wc * 64 + ni * 16 + m, ks * 4 + q);
#pragma unroll
      for (int mi = 0; mi < 4; mi++)
#pragma unroll
        for (int ni = 0; ni < 4; ni++)
          acc[mi][ni] = __builtin_amdgcn_mfma_f32_16x16x32_bf16(af[mi], bfr[ni], acc[mi][ni], 0, 0, 0);
    }
    __builtin_amdgcn_s_setprio(0);
    __syncthreads();  // prefetch landed + this tile's readers done
  }
  // (final loop barrier above: GEMM tile readers done -> dh planes writable)

  // ---- epilogue: this wave owns tree t0+wc, rows wr*64..+63 ----
  uchar4 flv[4];
#pragma unroll
  for (int mi = 0; mi < 4; mi++)
    flv[mi] = *(const uchar4*)(flags + bm0 + wr * 64 + mi * 16 + q * 4);
  float2 wpair = *(const float2*)(wbt + grow * 64 + t0);  // prefetch weights

  {
    int t = t0 + wc;
    float nk2 = -1.44269504089f / tree_temp[t];  // -itemp*log2(e)
    float ncb[4];
#pragma unroll
    for (int ni = 0; ni < 4; ni++) {
      int node = ni * 16 + m;
      ncb[ni] = ((node < 63) ? tree_b[t * 63 + node] : 0.f) * nk2;
    }
#pragma unroll
    for (int mi = 0; mi < 4; mi++) {
      unsigned char fl[4] = {flv[mi].x, flv[mi].y, flv[mi].z, flv[mi].w};
#pragma unroll
      for (int ni = 0; ni < 4; ni++) {
        int node = ni * 16 + m;
        f32x4 a = acc[mi][ni];
#pragma unroll
        for (int r4 = 0; r4 < 4; r4++) {
          int row = wr * 64 + mi * 16 + q * 4 + r4;
          float e = exp2f(fmaf(a[r4], nk2, ncb[ni]));
          float sig = __builtin_amdgcn_rcpf(1.f + e);
          unsigned short hv = __half_as_ushort(__float2half(sig));
          hv = fl[r4] ? (unsigned short)0x3800 : hv;  // miss -> 0.5h
          dh[wc * HPLANE + row * HSTRIDE + node + 1] = hv;
        }
      }
    }
  }
  __syncthreads();

  // ---- routing + leaf for both trees (independent chains -> ILP) ----
  float pc[10];
#pragma unroll
  for (int c = 0; c < 10; c++) pc[c] = 0.f;

#pragma unroll
  for (int tt = 0; tt < 2; ++tt) {
    int t = t0 + tt;
    const unsigned short* dr = dh + tt * HPLANE + row_l * HSTRIDE;
    float R[16];
    {
      float d0 = __half2float(__ushort_as_half(dr[1]));
      R[0] = d0;
      R[1] = 1.f - d0;
    }
#pragma unroll
    for (int L = 1; L <= 3; ++L) {
      int half = 1 << L;
#pragma unroll
      for (int g = 0; g < half; g += 2) {
        float2 dd = __half22float2(*reinterpret_cast<const __half2*>(dr + half + g));
        float ra = R[g] * dd.x;
        R[g + half] = R[g] - ra;
        R[g] = ra;
        float rb = R[g + 1] * dd.y;
        R[g + 1 + half] = R[g + 1] - rb;
        R[g + 1] = rb;
      }
    }
#pragma unroll
    for (int p = 0; p < 16; p += 2) {
      float2 dd = __half22float2(*reinterpret_cast<const __half2*>(dr + 16 + p));
      float da = h ? (1.f - dd.x) : dd.x;
      float db = h ? (1.f - dd.y) : dd.y;
      R[p] *= da;
      R[p + 1] *= db;
    }
    float a10[10];
#pragma unroll
    for (int c = 0; c < 10; c++) a10[c] = 0.f;
    const float* Lf = leaf + (size_t)(t * 64 + 16 * h) * 10;
#pragma unroll
    for (int p = 0; p < 16; p += 2) {
      float2 dd = __half22float2(*reinterpret_cast<const __half2*>(dr + 32 + 16 * h + p));
      float rla = R[p] * dd.x, rra = R[p] - rla;
      float rlb = R[p + 1] * dd.y, rrb = R[p + 1] - rlb;
#pragma unroll
      for (int c = 0; c < 10; c++) {
        float s = fmaf(rla, Lf[p * 10 + c], a10[c]);
        s = fmaf(rra, Lf[320 + p * 10 + c], s);
        s = fmaf(rlb, Lf[p * 10 + 10 + c], s);
        a10[c] = fmaf(rrb, Lf[330 + p * 10 + c], s);
      }
    }
    float w = tt ? wpair.y : wpair.x;
#pragma unroll
    for (int c = 0; c < 10; c++) pc[c] = fmaf(w, a10[c], pc[c]);
  }

  // ---- combine halves in LDS, one non-atomic bf16 partial row per block ----
  __syncthreads();
  float* redbuf = reinterpret_cast<float*>(smem);  // 128 x 10 f32
  if (h == 1) {
#pragma unroll
    for (int c = 0; c < 10; c++) redbuf[row_l * 10 + c] = pc[c];
  }
  __syncthreads();
  if (h == 0) {
    unsigned short* po = part + ((size_t)grow * 32 + blockIdx.x) * 10;
    unsigned wdw[5];
#pragma unroll
    for (int k = 0; k < 5; k++) {
      unsigned lo = f2bf(pc[2 * k] + redbuf[row_l * 10 + 2 * k]);
      unsigned hi = f2bf(pc[2 * k + 1] + redbuf[row_l * 10 + 2 * k + 1]);
      wdw[k] = lo | (hi << 16);
    }
    unsigned* pu = reinterpret_cast<unsigned*>(po);
#pragma unroll
    for (int k = 0; k < 5; k++) pu[k] = wdw[k];
  }
}

// ---------------- final: reduce 32 bf16 slices + softmax ----------------
__global__ void __launch_bounds__(128) k_finish(const unsigned short* __restrict__ part,
                                               float* __restrict__ out) {
  int row = blockIdx.x * 128 + threadIdx.x;
  const uint4* pu = reinterpret_cast<const uint4*>(part + (size_t)row * 320);
  float v[10];
#pragma unroll
  for (int c = 0; c < 10; c++) v[c] = 0.f;
#pragma unroll
  for (int ch = 0; ch < 8; ++ch) {
    uint4 w0 = pu[ch * 5 + 0];
    uint4 w1 = pu[ch * 5 + 1];
    uint4 w2 = pu[ch * 5 + 2];
    uint4 w3 = pu[ch * 5 + 3];
    uint4 w4 = pu[ch * 5 + 4];
    unsigned dw[20] = {w0.x, w0.y, w0.z, w0.w, w1.x, w1.y, w1.z, w1.w,
                       w2.x, w2.y, w2.z, w2.w, w3.x, w3.y, w3.z, w3.w,
                       w4.x, w4.y, w4.z, w4.w};
#pragma unroll
    for (int d = 0; d < 20; d++) {
      int k = d % 5;
      v[2 * k] += bflo(dw[d]);
      v[2 * k + 1] += bfhi(dw[d]);
    }
  }
  float mx = -1e30f;
#pragma unroll
  for (int c = 0; c < 10; c++) mx = fmaxf(mx, v[c]);
  float sm = 0.f;
#pragma unroll
  for (int c = 0; c < 10; c++) {
    v[c] = __expf(v[c] - mx);
    sm += v[c];
  }
  float inv = 1.f / sm;
#pragma unroll
  for (int c = 0; c < 10; c++) out[row * 10 + c] = v[c] * inv;
}

extern "C" void kernel_launch(void* const* d_in, const int* in_sizes, int n_in,
                              void* d_out, int out_size, void* d_ws, size_t ws_size,
                              hipStream_t stream) {
  const float* x    = (const float*)d_in[0];
  const float* w1   = (const float*)d_in[1];
  const float* b1   = (const float*)d_in[2];
  const float* gam  = (const float*)d_in[3];
  const float* bet  = (const float*)d_in[4];
  const float* mu   = (const float*)d_in[5];
  const float* var  = (const float*)d_in[6];
  const float* w2   = (const float*)d_in[7];
  const float* b2   = (const float*)d_in[8];
  const float* tw   = (const float*)d_in[9];
  const float* tb   = (const float*)d_in[10];
  const float* temp = (const float*)d_in[11];
  const float* leaf = (const float*)d_in[12];
  const float* rw   = (const float*)d_in[13];
  float* out = (float*)d_out;

  char* ws = (char*)d_ws;
  unsigned short* xc  = (unsigned short*)(ws);             // 16,777,216 B
  unsigned short* twb = (unsigned short*)(ws + 16777216);  //  4,194,304 B
  unsigned short* w1t = (unsigned short*)(ws + 20971520);  //    131,072 B
  float* wbt  = (float*)(ws + 21102592);                   //  4,194,304 B
  unsigned char* flg = (unsigned char*)(ws + 25296896);    //     16,384 B
  unsigned short* part = (unsigned short*)(ws + 25362432); // 10,485,760 B

  k_prep<<<5376, 256, 0, stream>>>(tw, twb, w1, w1t, x, xc, flg);
  k_attn<<<512, 256, 0, stream>>>(xc, w1t, b1, gam, bet, mu, var,
                                  w2, b2, rw, wbt);
  dim3 g2(32, 128);
  k_trees<<<g2, 256, 0, stream>>>(xc, twb, tb, temp, leaf, wbt, flg, part);
  k_finish<<<128, 128, 0, stream>>>(part, out);
}

// Round 10
// 246.231 us; speedup vs baseline: 1.0002x; 1.0002x over previous
//
#include <hip/hip_runtime.h>
#include <hip/hip_fp16.h>
#include <stdint.h>

#define IN_DIM 512
#define NT 64
#define AH 128
#define NCLS 10
#define BN_EPS_C 1e-5f
#define SHRINK 0.3f
#define HSTRIDE 66   // f16 decision plane stride: 66 h16 = 33 dw, coprime mod 32
#define HPLANE 8448  // 128 * 66 h16 per tree plane

typedef __bf16 bf16x8 __attribute__((ext_vector_type(8)));
typedef float f32x4 __attribute__((ext_vector_type(4)));
typedef unsigned int u32x4 __attribute__((ext_vector_type(4)));

__device__ __forceinline__ unsigned short f2bf(float f) {
  unsigned u = __builtin_bit_cast(unsigned, f);
  u += 0x7fffu + ((u >> 16) & 1u);   // RNE; inputs are NaN-free after NaN-zeroing
  return (unsigned short)(u >> 16);
}

__device__ __forceinline__ float bflo(unsigned w) {
  return __builtin_bit_cast(float, w << 16);
}
__device__ __forceinline__ float bfhi(unsigned w) {
  return __builtin_bit_cast(float, w & 0xffff0000u);
}

__device__ __forceinline__ void gload_lds16(const void* g, void* l) {
  __builtin_amdgcn_global_load_lds(
      (const __attribute__((address_space(1))) void*)g,
      (__attribute__((address_space(3))) void*)l, 16, 0, 0);
}

// read one 16B MFMA fragment from a swizzled [rows][64] bf16 LDS tile (BK=64)
// row stride 128B == 0 mod 32 banks; 8-deep XOR -> 16-row frag read is 2-way
// (free). R2 lesson: BK=32 (64B stride, 4-deep XOR) is 4-way -> 5x conflicts.
__device__ __forceinline__ bf16x8 frag_ld(const char* lds, int r, int q) {
  return *reinterpret_cast<const bf16x8*>(lds + r * 128 + ((q ^ (r & 7)) * 16));
}

// stage one 128x64 A tile + 128x64 B tile (BK=64, 16KB each)
__device__ __forceinline__ void stage_trees(const unsigned short* Ak,
                                            const unsigned short* Bk,
                                            char* As, char* Bs,
                                            int wid, int sub, int cpos) {
#pragma unroll
  for (int i = 0; i < 4; i++) {
    int seg = wid * 4 + i;
    int r = seg * 8 + sub;
    int cg = cpos ^ (r & 7);
    gload_lds16(Ak + r * 512 + cg * 8, As + seg * 1024);
    gload_lds16(Bk + r * 512 + cg * 8, Bs + seg * 1024);
  }
}

// ------ prep: tree_w->bf16(pad), w1->w1t, x->xc+flags (R7 config) ----------
// R6 lesson: NO device-scope fences in hot kernels. Cross-kernel stream
// order is the cheap sync. x-conversion here runs at full HBM width.
__global__ void __launch_bounds__(256) k_prep(
    const float* __restrict__ tw, unsigned short* __restrict__ twb,
    const float* __restrict__ w1, unsigned short* __restrict__ w1t,
    const float* __restrict__ x, unsigned short* __restrict__ xc,
    unsigned char* __restrict__ flags) {
  int b = blockIdx.x;
  if (b < 1024) {
    int tid = b * 256 + threadIdx.x;  // 262144
    int o = tid * 8;
    int k = o & 511;
    int nt = o >> 9;
    int node = nt & 63, t = nt >> 6;
    union { unsigned short s[8]; u32x4 u; } pk;
    if (node < 63) {
      const float* p = tw + ((t * 63 + node) * 512 + k);
      float4 a = *(const float4*)p, bb = *(const float4*)(p + 4);
      float v[8] = {a.x, a.y, a.z, a.w, bb.x, bb.y, bb.z, bb.w};
#pragma unroll
      for (int i = 0; i < 8; i++) pk.s[i] = f2bf(v[i]);
    } else {
#pragma unroll
      for (int i = 0; i < 8; i++) pk.s[i] = 0;
    }
    *reinterpret_cast<u32x4*>(twb + o) = pk.u;
  } else if (b < 1280) {
    int tid = (b - 1024) * 256 + threadIdx.x;  // 65536
    int k = tid & 511, n = tid >> 9;
    w1t[n * 512 + k] = f2bf(w1[k * 128 + n]);
  } else {
    // x -> xc + flags: one wave per row
    int tid = (b - 1280) * 256 + threadIdx.x;  // 0..1048575
    int row = tid >> 6;
    int lane = threadIdx.x & 63;
    const float* px = x + (size_t)row * 512 + lane * 8;
    float4 a = *(const float4*)px;
    float4 bb = *(const float4*)(px + 4);
    float v[8] = {a.x, a.y, a.z, a.w, bb.x, bb.y, bb.z, bb.w};
    bool nan_any = false;
    union { unsigned short s[8]; u32x4 u; } pk;
#pragma unroll
    for (int j = 0; j < 8; j++) {
      bool n = (v[j] != v[j]);
      nan_any |= n;
      pk.s[j] = f2bf(n ? 0.f : v[j]);
    }
    *reinterpret_cast<u32x4*>(xc + (size_t)row * 512 + lane * 8) = pk.u;
    unsigned long long bal = __ballot(nan_any);
    if (lane == 0) flags[row] = bal ? 1 : 0;
  }
}

// ---------------- attention: 32-row tiles, 512 blocks = 2/CU (R8 config) ---
// R9 lesson: setprio around MFMA is null-to-negative here too (barrier-locked
// waves within block; prioritizing compute starves the co-resident block's
// prefetch). Plain R8 loop restored.
__global__ void __launch_bounds__(256) k_attn(
    const unsigned short* __restrict__ xc,
    const unsigned short* __restrict__ w1t,
    const float* __restrict__ b1, const float* __restrict__ gam,
    const float* __restrict__ bet, const float* __restrict__ mu,
    const float* __restrict__ var, const float* __restrict__ w2,
    const float* __restrict__ b2, const float* __restrict__ rw,
    float* __restrict__ wbt) {
  __shared__ __align__(16) char smem[46592];
  char* As = smem;                                        // 32x64 bf16 = 4096
  char* Bs = smem + 4096;                                 // 128x64 bf16 = 16384
  unsigned short* hb  = (unsigned short*)(smem + 20480);  // [32][136] bf16 = 8704
  unsigned short* w2s = (unsigned short*)(smem + 29184);  // [64][136] bf16 = 17408
  int lane = threadIdx.x & 63, wid = threadIdx.x >> 6;
  int bm0 = blockIdx.x * 32;
  int m = lane & 15, q = lane >> 4;
  int sub = lane >> 3, cpos = lane & 7;
  int wr = wid & 1, wc = wid >> 1;   // wave grid 2x2 over 32 rows x 128 cols

  for (int i = threadIdx.x; i < AH * NT; i += 256) {
    int k = i >> 6, n = i & 63;
    w2s[n * 136 + k] = f2bf(w2[i]);
  }
  __syncthreads();  // w2s visible

  f32x4 acc[4];
#pragma unroll
  for (int j = 0; j < 4; j++) acc[j] = f32x4{0.f, 0.f, 0.f, 0.f};
  const unsigned short* Ag = xc + (size_t)bm0 * 512;

  for (int ko = 0; ko < 8; ++ko) {
    const unsigned short* Ak = Ag + ko * 64;
    const unsigned short* Bk = w1t + ko * 64;
    {  // A: 4 segs (32 rows), one per wave
      int seg = wid;
      int r = seg * 8 + sub;
      int cg = cpos ^ (r & 7);
      gload_lds16(Ak + r * 512 + cg * 8, As + seg * 1024);
    }
#pragma unroll
    for (int i = 0; i < 4; i++) {  // B: 16 segs, 4 per wave
      int seg = wid * 4 + i;
      int r = seg * 8 + sub;
      int cg = cpos ^ (r & 7);
      gload_lds16(Bk + r * 512 + cg * 8, Bs + seg * 1024);
    }
    __syncthreads();
#pragma unroll
    for (int ks = 0; ks < 2; ++ks) {
      bf16x8 af = frag_ld(As, wr * 16 + m, ks * 4 + q);
#pragma unroll
      for (int ni = 0; ni < 4; ni++) {
        bf16x8 bfr = frag_ld(Bs, wc * 64 + ni * 16 + m, ks * 4 + q);
        acc[ni] = __builtin_amdgcn_mfma_f32_16x16x32_bf16(af, bfr, acc[ni], 0, 0, 0);
      }
    }
    __syncthreads();
  }

  // BN epilogue: wave (wr,wc) owns rows wr*16..+16, cols wc*64..+64
#pragma unroll
  for (int ni = 0; ni < 4; ni++) {
    int col = wc * 64 + ni * 16 + m;
    float bb = b1[col], ga = gam[col], be = bet[col], mm = mu[col];
    float iv = rsqrtf(var[col] + BN_EPS_C);
#pragma unroll
    for (int r4 = 0; r4 < 4; r4++) {
      int rl = wr * 16 + q * 4 + r4;
      float v = acc[ni][r4] + bb;
      v = fmaxf(v, 0.f);
      v = (v - mm) * iv * ga + be;
      hb[rl * 136 + col] = f2bf(v);
    }
  }
  __syncthreads();

  // GEMM2 + softmax on waves 0-1 (wave w: rows w*16..+16, all 64 trees)
  if (wid < 2) {
    f32x4 acc2[4];
#pragma unroll
    for (int nt = 0; nt < 4; nt++) acc2[nt] = f32x4{0.f, 0.f, 0.f, 0.f};
#pragma unroll
    for (int ks = 0; ks < 4; ++ks) {
      bf16x8 af = *reinterpret_cast<const bf16x8*>(hb + (wid * 16 + m) * 136 + ks * 32 + q * 8);
#pragma unroll
      for (int nt = 0; nt < 4; nt++) {
        bf16x8 bfr = *reinterpret_cast<const bf16x8*>(w2s + (nt * 16 + m) * 136 + ks * 32 + q * 8);
        acc2[nt] = __builtin_amdgcn_mfma_f32_16x16x32_bf16(af, bfr, acc2[nt], 0, 0, 0);
      }
    }

    float b2v[4], cfv[4];
#pragma unroll
    for (int nt = 0; nt < 4; nt++) {
      int col = nt * 16 + m;
      b2v[nt] = b2[col];
      cfv[nt] = SHRINK * rw[col];
    }
#pragma unroll
    for (int reg = 0; reg < 4; ++reg) {
      float s0 = acc2[0][reg] + b2v[0];
      float s1 = acc2[1][reg] + b2v[1];
      float s2 = acc2[2][reg] + b2v[2];
      float s3 = acc2[3][reg] + b2v[3];
      float mx = fmaxf(fmaxf(s0, s1), fmaxf(s2, s3));
#pragma unroll
      for (int o = 1; o < 16; o <<= 1) mx = fmaxf(mx, __shfl_xor(mx, o));
      float e0 = __expf(s0 - mx), e1 = __expf(s1 - mx);
      float e2 = __expf(s2 - mx), e3 = __expf(s3 - mx);
      float sm = e0 + e1 + e2 + e3;
#pragma unroll
      for (int o = 1; o < 16; o <<= 1) sm += __shfl_xor(sm, o);
      float inv = 1.f / sm;
      int row = bm0 + wid * 16 + q * 4 + reg;
      wbt[row * NT + m]      = e0 * inv * cfv[0];
      wbt[row * NT + 16 + m] = e1 * inv * cfv[1];
      wbt[row * NT + 32 + m] = e2 * inv * cfv[2];
      wbt[row * NT + 48 + m] = e3 * inv * cfv[3];
    }
  }
}

// ---------------- main: tree logits + routing + leaf -> per-slice partials ----
// FINAL: frozen R3/R7 structure (127.3-128.8us across 6 rounds): BK=64
// gload_lds double-buffer, prefetch-before-compute, ONE barrier per ko,
// 2x2 wave grid. Falsified levers: BK=32 (R2: 4-way conflicts), A-reg
// staging (R4: +1 barrier = +15us), LDS shrink (R2/R4: occupancy pinned
// ~21%), in-kernel fence finish (R6: 3x regression), fused prep (R5),
// setprio on MFMA cluster (R9: +3us, starves co-resident prefetch).
__global__ void __launch_bounds__(256) k_trees(
    const unsigned short* __restrict__ xc,   // [16384][512]
    const unsigned short* __restrict__ twb,  // [64*64][512]
    const float* __restrict__ tree_b,        // [64][63]
    const float* __restrict__ tree_temp,     // [64]
    const float* __restrict__ leaf,          // [64][64][10]
    const float* __restrict__ wbt,           // [16384][64]
    const unsigned char* __restrict__ flags, // [16384]
    unsigned short* __restrict__ part) {     // [16384][32][10] bf16
  __shared__ __align__(16) char smem[65536];
  char* A0 = smem;                                  // 128x64 bf16 = 16384
  char* B0 = smem + 16384;
  char* A1 = smem + 32768;
  char* B1 = smem + 49152;
  unsigned short* dh = (unsigned short*)smem;       // 2 planes x 128 x 66 f16 = 33792
  int lane = threadIdx.x & 63, wid = threadIdx.x >> 6;
  int bm0 = blockIdx.y * 128;   // row tile
  int t0 = blockIdx.x * 2;      // tree pair (fast grid dim for L2 sharing)
  int m = lane & 15, q = lane >> 4;
  int sub = lane >> 3, cpos = lane & 7;
  int wr = wid >> 1, wc = wid & 1;   // wave grid 2x2 over 128 rows x 128 cols
  int row_l = threadIdx.x & 127;
  int h = __builtin_amdgcn_readfirstlane((int)(threadIdx.x >> 7));  // wave-uniform half
  int grow = bm0 + row_l;

  f32x4 acc[4][4];
#pragma unroll
  for (int i = 0; i < 4; i++)
#pragma unroll
    for (int j = 0; j < 4; j++) acc[i][j] = f32x4{0.f, 0.f, 0.f, 0.f};

  const unsigned short* Ag = xc + (size_t)bm0 * 512;
  const unsigned short* Bg = twb + (size_t)t0 * 64 * 512;

  stage_trees(Ag, Bg, A0, B0, wid, sub, cpos);
  __syncthreads();  // prologue stage landed (only exposed drain)

#pragma unroll
  for (int ko = 0; ko < 8; ++ko) {
    char* As = (ko & 1) ? A1 : A0;
    char* Bs = (ko & 1) ? B1 : B0;
    if (ko < 7) {  // prefetch next K-tile BEFORE compute
      char* An = (ko & 1) ? A0 : A1;
      char* Bn = (ko & 1) ? B0 : B1;
      stage_trees(Ag + (ko + 1) * 64, Bg + (ko + 1) * 64, An, Bn, wid, sub, cpos);
    }
#pragma unroll
    for (int ks = 0; ks < 2; ++ks) {
      bf16x8 af[4], bfr[4];
#pragma unroll
      for (int mi = 0; mi < 4; mi++) af[mi] = frag_ld(As, wr * 64 + mi * 16 + m, ks * 4 + q);
#pragma unroll
      for (int ni = 0; ni < 4; ni++) bfr[ni] = frag_ld(Bs, wc * 64 + ni * 16 + m, ks * 4 + q);
#pragma unroll
      for (int mi = 0; mi < 4; mi++)
#pragma unroll
        for (int ni = 0; ni < 4; ni++)
          acc[mi][ni] = __builtin_amdgcn_mfma_f32_16x16x32_bf16(af[mi], bfr[ni], acc[mi][ni], 0, 0, 0);
    }
    __syncthreads();  // prefetch landed + this tile's readers done
  }
  // (final loop barrier above: GEMM tile readers done -> dh planes writable)

  // ---- epilogue: this wave owns tree t0+wc, rows wr*64..+63 ----
  uchar4 flv[4];
#pragma unroll
  for (int mi = 0; mi < 4; mi++)
    flv[mi] = *(const uchar4*)(flags + bm0 + wr * 64 + mi * 16 + q * 4);
  float2 wpair = *(const float2*)(wbt + grow * 64 + t0);  // prefetch weights

  {
    int t = t0 + wc;
    float nk2 = -1.44269504089f / tree_temp[t];  // -itemp*log2(e)
    float ncb[4];
#pragma unroll
    for (int ni = 0; ni < 4; ni++) {
      int node = ni * 16 + m;
      ncb[ni] = ((node < 63) ? tree_b[t * 63 + node] : 0.f) * nk2;
    }
#pragma unroll
    for (int mi = 0; mi < 4; mi++) {
      unsigned char fl[4] = {flv[mi].x, flv[mi].y, flv[mi].z, flv[mi].w};
#pragma unroll
      for (int ni = 0; ni < 4; ni++) {
        int node = ni * 16 + m;
        f32x4 a = acc[mi][ni];
#pragma unroll
        for (int r4 = 0; r4 < 4; r4++) {
          int row = wr * 64 + mi * 16 + q * 4 + r4;
          float e = exp2f(fmaf(a[r4], nk2, ncb[ni]));
          float sig = __builtin_amdgcn_rcpf(1.f + e);
          unsigned short hv = __half_as_ushort(__float2half(sig));
          hv = fl[r4] ? (unsigned short)0x3800 : hv;  // miss -> 0.5h
          dh[wc * HPLANE + row * HSTRIDE + node + 1] = hv;
        }
      }
    }
  }
  __syncthreads();

  // ---- routing + leaf for both trees (independent chains -> ILP) ----
  float pc[10];
#pragma unroll
  for (int c = 0; c < 10; c++) pc[c] = 0.f;

#pragma unroll
  for (int tt = 0; tt < 2; ++tt) {
    int t = t0 + tt;
    const unsigned short* dr = dh + tt * HPLANE + row_l * HSTRIDE;
    float R[16];
    {
      float d0 = __half2float(__ushort_as_half(dr[1]));
      R[0] = d0;
      R[1] = 1.f - d0;
    }
#pragma unroll
    for (int L = 1; L <= 3; ++L) {
      int half = 1 << L;
#pragma unroll
      for (int g = 0; g < half; g += 2) {
        float2 dd = __half22float2(*reinterpret_cast<const __half2*>(dr + half + g));
        float ra = R[g] * dd.x;
        R[g + half] = R[g] - ra;
        R[g] = ra;
        float rb = R[g + 1] * dd.y;
        R[g + 1 + half] = R[g + 1] - rb;
        R[g + 1] = rb;
      }
    }
#pragma unroll
    for (int p = 0; p < 16; p += 2) {
      float2 dd = __half22float2(*reinterpret_cast<const __half2*>(dr + 16 + p));
      float da = h ? (1.f - dd.x) : dd.x;
      float db = h ? (1.f - dd.y) : dd.y;
      R[p] *= da;
      R[p + 1] *= db;
    }
    float a10[10];
#pragma unroll
    for (int c = 0; c < 10; c++) a10[c] = 0.f;
    const float* Lf = leaf + (size_t)(t * 64 + 16 * h) * 10;
#pragma unroll
    for (int p = 0; p < 16; p += 2) {
      float2 dd = __half22float2(*reinterpret_cast<const __half2*>(dr + 32 + 16 * h + p));
      float rla = R[p] * dd.x, rra = R[p] - rla;
      float rlb = R[p + 1] * dd.y, rrb = R[p + 1] - rlb;
#pragma unroll
      for (int c = 0; c < 10; c++) {
        float s = fmaf(rla, Lf[p * 10 + c], a10[c]);
        s = fmaf(rra, Lf[320 + p * 10 + c], s);
        s = fmaf(rlb, Lf[p * 10 + 10 + c], s);
        a10[c] = fmaf(rrb, Lf[330 + p * 10 + c], s);
      }
    }
    float w = tt ? wpair.y : wpair.x;
#pragma unroll
    for (int c = 0; c < 10; c++) pc[c] = fmaf(w, a10[c], pc[c]);
  }

  // ---- combine halves in LDS, one non-atomic bf16 partial row per block ----
  __syncthreads();
  float* redbuf = reinterpret_cast<float*>(smem);  // 128 x 10 f32
  if (h == 1) {
#pragma unroll
    for (int c = 0; c < 10; c++) redbuf[row_l * 10 + c] = pc[c];
  }
  __syncthreads();
  if (h == 0) {
    unsigned short* po = part + ((size_t)grow * 32 + blockIdx.x) * 10;
    unsigned wdw[5];
#pragma unroll
    for (int k = 0; k < 5; k++) {
      unsigned lo = f2bf(pc[2 * k] + redbuf[row_l * 10 + 2 * k]);
      unsigned hi = f2bf(pc[2 * k + 1] + redbuf[row_l * 10 + 2 * k + 1]);
      wdw[k] = lo | (hi << 16);
    }
    unsigned* pu = reinterpret_cast<unsigned*>(po);
#pragma unroll
    for (int k = 0; k < 5; k++) pu[k] = wdw[k];
  }
}

// ---------------- final: reduce 32 bf16 slices + softmax ----------------
__global__ void __launch_bounds__(128) k_finish(const unsigned short* __restrict__ part,
                                               float* __restrict__ out) {
  int row = blockIdx.x * 128 + threadIdx.x;
  const uint4* pu = reinterpret_cast<const uint4*>(part + (size_t)row * 320);
  float v[10];
#pragma unroll
  for (int c = 0; c < 10; c++) v[c] = 0.f;
#pragma unroll
  for (int ch = 0; ch < 8; ++ch) {
    uint4 w0 = pu[ch * 5 + 0];
    uint4 w1 = pu[ch * 5 + 1];
    uint4 w2 = pu[ch * 5 + 2];
    uint4 w3 = pu[ch * 5 + 3];
    uint4 w4 = pu[ch * 5 + 4];
    unsigned dw[20] = {w0.x, w0.y, w0.z, w0.w, w1.x, w1.y, w1.z, w1.w,
                       w2.x, w2.y, w2.z, w2.w, w3.x, w3.y, w3.z, w3.w,
                       w4.x, w4.y, w4.z, w4.w};
#pragma unroll
    for (int d = 0; d < 20; d++) {
      int k = d % 5;
      v[2 * k] += bflo(dw[d]);
      v[2 * k + 1] += bfhi(dw[d]);
    }
  }
  float mx = -1e30f;
#pragma unroll
  for (int c = 0; c < 10; c++) mx = fmaxf(mx, v[c]);
  float sm = 0.f;
#pragma unroll
  for (int c = 0; c < 10; c++) {
    v[c] = __expf(v[c] - mx);
    sm += v[c];
  }
  float inv = 1.f / sm;
#pragma unroll
  for (int c = 0; c < 10; c++) out[row * 10 + c] = v[c] * inv;
}

extern "C" void kernel_launch(void* const* d_in, const int* in_sizes, int n_in,
                              void* d_out, int out_size, void* d_ws, size_t ws_size,
                              hipStream_t stream) {
  const float* x    = (const float*)d_in[0];
  const float* w1   = (const float*)d_in[1];
  const float* b1   = (const float*)d_in[2];
  const float* gam  = (const float*)d_in[3];
  const float* bet  = (const float*)d_in[4];
  const float* mu   = (const float*)d_in[5];
  const float* var  = (const float*)d_in[6];
  const float* w2   = (const float*)d_in[7];
  const float* b2   = (const float*)d_in[8];
  const float* tw   = (const float*)d_in[9];
  const float* tb   = (const float*)d_in[10];
  const float* temp = (const float*)d_in[11];
  const float* leaf = (const float*)d_in[12];
  const float* rw   = (const float*)d_in[13];
  float* out = (float*)d_out;

  char* ws = (char*)d_ws;
  unsigned short* xc  = (unsigned short*)(ws);             // 16,777,216 B
  unsigned short* twb = (unsigned short*)(ws + 16777216);  //  4,194,304 B
  unsigned short* w1t = (unsigned short*)(ws + 20971520);  //    131,072 B
  float* wbt  = (float*)(ws + 21102592);                   //  4,194,304 B
  unsigned char* flg = (unsigned char*)(ws + 25296896);    //     16,384 B
  unsigned short* part = (unsigned short*)(ws + 25362432); // 10,485,760 B

  k_prep<<<5376, 256, 0, stream>>>(tw, twb, w1, w1t, x, xc, flg);
  k_attn<<<512, 256, 0, stream>>>(xc, w1t, b1, gam, bet, mu, var,
                                  w2, b2, rw, wbt);
  dim3 g2(32, 128);
  k_trees<<<g2, 256, 0, stream>>>(xc, twb, tb, temp, leaf, wbt, flg, part);
  k_finish<<<128, 128, 0, stream>>>(part, out);
}

// Round 11
// 225.415 us; speedup vs baseline: 1.0926x; 1.0923x over previous
//
#include <hip/hip_runtime.h>
#include <hip/hip_fp16.h>
#include <stdint.h>

#define IN_DIM 512
#define NT 64
#define AH 128
#define NCLS 10
#define BN_EPS_C 1e-5f
#define SHRINK 0.3f
#define HSTRIDE 66   // f16 decision plane stride: 66 h16 = 33 dw, coprime mod 32
#define HPLANE 8448  // 128 * 66 h16 per tree plane

typedef __bf16 bf16x8 __attribute__((ext_vector_type(8)));
typedef float f32x4 __attribute__((ext_vector_type(4)));
typedef unsigned int u32x4 __attribute__((ext_vector_type(4)));

__device__ __forceinline__ unsigned short f2bf(float f) {
  unsigned u = __builtin_bit_cast(unsigned, f);
  u += 0x7fffu + ((u >> 16) & 1u);   // RNE; inputs are NaN-free after NaN-zeroing
  return (unsigned short)(u >> 16);
}

__device__ __forceinline__ float bflo(unsigned w) {
  return __builtin_bit_cast(float, w << 16);
}
__device__ __forceinline__ float bfhi(unsigned w) {
  return __builtin_bit_cast(float, w & 0xffff0000u);
}

__device__ __forceinline__ void gload_lds16(const void* g, void* l) {
  __builtin_amdgcn_global_load_lds(
      (const __attribute__((address_space(1))) void*)g,
      (__attribute__((address_space(3))) void*)l, 16, 0, 0);
}

// read one 16B MFMA fragment from a swizzled [rows][64] bf16 LDS tile (BK=64)
// row stride 128B == 0 mod 32 banks; 8-deep XOR -> 16-row frag read is 2-way
// (free). R2 lesson: BK=32 (64B stride, 4-deep XOR) is 4-way -> 5x conflicts.
__device__ __forceinline__ bf16x8 frag_ld(const char* lds, int r, int q) {
  return *reinterpret_cast<const bf16x8*>(lds + r * 128 + ((q ^ (r & 7)) * 16));
}

// stage one 128x64 A tile + 128x64 B tile (BK=64, 16KB each)
__device__ __forceinline__ void stage_trees(const unsigned short* Ak,
                                            const unsigned short* Bk,
                                            char* As, char* Bs,
                                            int wid, int sub, int cpos) {
#pragma unroll
  for (int i = 0; i < 4; i++) {
    int seg = wid * 4 + i;
    int r = seg * 8 + sub;
    int cg = cpos ^ (r & 7);
    gload_lds16(Ak + r * 512 + cg * 8, As + seg * 1024);
    gload_lds16(Bk + r * 512 + cg * 8, Bs + seg * 1024);
  }
}

// ------ prep: tree_w->bf16(pad), w1->w1t, x->xc+flags (R7 config) ----------
// R6 lesson: NO device-scope fences in hot kernels. Cross-kernel stream
// order is the cheap sync. x-conversion here runs at full HBM width.
__global__ void __launch_bounds__(256) k_prep(
    const float* __restrict__ tw, unsigned short* __restrict__ twb,
    const float* __restrict__ w1, unsigned short* __restrict__ w1t,
    const float* __restrict__ x, unsigned short* __restrict__ xc,
    unsigned char* __restrict__ flags) {
  int b = blockIdx.x;
  if (b < 1024) {
    int tid = b * 256 + threadIdx.x;  // 262144
    int o = tid * 8;
    int k = o & 511;
    int nt = o >> 9;
    int node = nt & 63, t = nt >> 6;
    union { unsigned short s[8]; u32x4 u; } pk;
    if (node < 63) {
      const float* p = tw + ((t * 63 + node) * 512 + k);
      float4 a = *(const float4*)p, bb = *(const float4*)(p + 4);
      float v[8] = {a.x, a.y, a.z, a.w, bb.x, bb.y, bb.z, bb.w};
#pragma unroll
      for (int i = 0; i < 8; i++) pk.s[i] = f2bf(v[i]);
    } else {
#pragma unroll
      for (int i = 0; i < 8; i++) pk.s[i] = 0;
    }
    *reinterpret_cast<u32x4*>(twb + o) = pk.u;
  } else if (b < 1280) {
    int tid = (b - 1024) * 256 + threadIdx.x;  // 65536
    int k = tid & 511, n = tid >> 9;
    w1t[n * 512 + k] = f2bf(w1[k * 128 + n]);
  } else {
    // x -> xc + flags: one wave per row
    int tid = (b - 1280) * 256 + threadIdx.x;  // 0..1048575
    int row = tid >> 6;
    int lane = threadIdx.x & 63;
    const float* px = x + (size_t)row * 512 + lane * 8;
    float4 a = *(const float4*)px;
    float4 bb = *(const float4*)(px + 4);
    float v[8] = {a.x, a.y, a.z, a.w, bb.x, bb.y, bb.z, bb.w};
    bool nan_any = false;
    union { unsigned short s[8]; u32x4 u; } pk;
#pragma unroll
    for (int j = 0; j < 8; j++) {
      bool n = (v[j] != v[j]);
      nan_any |= n;
      pk.s[j] = f2bf(n ? 0.f : v[j]);
    }
    *reinterpret_cast<u32x4*>(xc + (size_t)row * 512 + lane * 8) = pk.u;
    unsigned long long bal = __ballot(nan_any);
    if (lane == 0) flags[row] = bal ? 1 : 0;
  }
}

// ---------------- attention: 32-row tiles, 512 blocks = 2/CU (R8 config) ---
__global__ void __launch_bounds__(256) k_attn(
    const unsigned short* __restrict__ xc,
    const unsigned short* __restrict__ w1t,
    const float* __restrict__ b1, const float* __restrict__ gam,
    const float* __restrict__ bet, const float* __restrict__ mu,
    const float* __restrict__ var, const float* __restrict__ w2,
    const float* __restrict__ b2, const float* __restrict__ rw,
    float* __restrict__ wbt) {
  __shared__ __align__(16) char smem[46592];
  char* As = smem;                                        // 32x64 bf16 = 4096
  char* Bs = smem + 4096;                                 // 128x64 bf16 = 16384
  unsigned short* hb  = (unsigned short*)(smem + 20480);  // [32][136] bf16 = 8704
  unsigned short* w2s = (unsigned short*)(smem + 29184);  // [64][136] bf16 = 17408
  int lane = threadIdx.x & 63, wid = threadIdx.x >> 6;
  int bm0 = blockIdx.x * 32;
  int m = lane & 15, q = lane >> 4;
  int sub = lane >> 3, cpos = lane & 7;
  int wr = wid & 1, wc = wid >> 1;   // wave grid 2x2 over 32 rows x 128 cols

  for (int i = threadIdx.x; i < AH * NT; i += 256) {
    int k = i >> 6, n = i & 63;
    w2s[n * 136 + k] = f2bf(w2[i]);
  }
  __syncthreads();  // w2s visible

  f32x4 acc[4];
#pragma unroll
  for (int j = 0; j < 4; j++) acc[j] = f32x4{0.f, 0.f, 0.f, 0.f};
  const unsigned short* Ag = xc + (size_t)bm0 * 512;

  for (int ko = 0; ko < 8; ++ko) {
    const unsigned short* Ak = Ag + ko * 64;
    const unsigned short* Bk = w1t + ko * 64;
    {  // A: 4 segs (32 rows), one per wave
      int seg = wid;
      int r = seg * 8 + sub;
      int cg = cpos ^ (r & 7);
      gload_lds16(Ak + r * 512 + cg * 8, As + seg * 1024);
    }
#pragma unroll
    for (int i = 0; i < 4; i++) {  // B: 16 segs, 4 per wave
      int seg = wid * 4 + i;
      int r = seg * 8 + sub;
      int cg = cpos ^ (r & 7);
      gload_lds16(Bk + r * 512 + cg * 8, Bs + seg * 1024);
    }
    __syncthreads();
#pragma unroll
    for (int ks = 0; ks < 2; ++ks) {
      bf16x8 af = frag_ld(As, wr * 16 + m, ks * 4 + q);
#pragma unroll
      for (int ni = 0; ni < 4; ni++) {
        bf16x8 bfr = frag_ld(Bs, wc * 64 + ni * 16 + m, ks * 4 + q);
        acc[ni] = __builtin_amdgcn_mfma_f32_16x16x32_bf16(af, bfr, acc[ni], 0, 0, 0);
      }
    }
    __syncthreads();
  }

  // BN epilogue: wave (wr,wc) owns rows wr*16..+16, cols wc*64..+64
#pragma unroll
  for (int ni = 0; ni < 4; ni++) {
    int col = wc * 64 + ni * 16 + m;
    float bb = b1[col], ga = gam[col], be = bet[col], mm = mu[col];
    float iv = rsqrtf(var[col] + BN_EPS_C);
#pragma unroll
    for (int r4 = 0; r4 < 4; r4++) {
      int rl = wr * 16 + q * 4 + r4;
      float v = acc[ni][r4] + bb;
      v = fmaxf(v, 0.f);
      v = (v - mm) * iv * ga + be;
      hb[rl * 136 + col] = f2bf(v);
    }
  }
  __syncthreads();

  // GEMM2 + softmax on waves 0-1 (wave w: rows w*16..+16, all 64 trees)
  if (wid < 2) {
    f32x4 acc2[4];
#pragma unroll
    for (int nt = 0; nt < 4; nt++) acc2[nt] = f32x4{0.f, 0.f, 0.f, 0.f};
#pragma unroll
    for (int ks = 0; ks < 4; ++ks) {
      bf16x8 af = *reinterpret_cast<const bf16x8*>(hb + (wid * 16 + m) * 136 + ks * 32 + q * 8);
#pragma unroll
      for (int nt = 0; nt < 4; nt++) {
        bf16x8 bfr = *reinterpret_cast<const bf16x8*>(w2s + (nt * 16 + m) * 136 + ks * 32 + q * 8);
        acc2[nt] = __builtin_amdgcn_mfma_f32_16x16x32_bf16(af, bfr, acc2[nt], 0, 0, 0);
      }
    }

    float b2v[4], cfv[4];
#pragma unroll
    for (int nt = 0; nt < 4; nt++) {
      int col = nt * 16 + m;
      b2v[nt] = b2[col];
      cfv[nt] = SHRINK * rw[col];
    }
#pragma unroll
    for (int reg = 0; reg < 4; ++reg) {
      float s0 = acc2[0][reg] + b2v[0];
      float s1 = acc2[1][reg] + b2v[1];
      float s2 = acc2[2][reg] + b2v[2];
      float s3 = acc2[3][reg] + b2v[3];
      float mx = fmaxf(fmaxf(s0, s1), fmaxf(s2, s3));
#pragma unroll
      for (int o = 1; o < 16; o <<= 1) mx = fmaxf(mx, __shfl_xor(mx, o));
      float e0 = __expf(s0 - mx), e1 = __expf(s1 - mx);
      float e2 = __expf(s2 - mx), e3 = __expf(s3 - mx);
      float sm = e0 + e1 + e2 + e3;
#pragma unroll
      for (int o = 1; o < 16; o <<= 1) sm += __shfl_xor(sm, o);
      float inv = 1.f / sm;
      int row = bm0 + wid * 16 + q * 4 + reg;
      wbt[row * NT + m]      = e0 * inv * cfv[0];
      wbt[row * NT + 16 + m] = e1 * inv * cfv[1];
      wbt[row * NT + 32 + m] = e2 * inv * cfv[2];
      wbt[row * NT + 48 + m] = e3 * inv * cfv[3];
    }
  }
}

// ---------------- main: tree logits + routing + leaf -> per-slice partials ----
// R21: frozen R3/R7 GEMM structure + XCD-chunked block remap (T1).
// Dispatch id = y*32+x, XCD ~ id%8 = x%8: each XCD held only 4 tree-pairs
// of twb (512KB, L2-hit) but swept ALL 16MB of xc -> ~128MB of L2 misses;
// each per-ko vmcnt(0) drain waits on the slowest (L3/HBM-latency) load.
// Remap: XCD c=(cx,cy) owns an 8x-by-64y chunk -> per-XCD working set
// 1MB twb + streamed xc panels (L2-fits); model traffic 128->48MB.
// Bijection: 4096 blocks = 8 XCDs x 512, nwg%8==0 (ERRATA #11 satisfied).
// Falsified levers: BK=32 (R2), A-reg staging (R4), LDS shrink (R2/R4),
// fence finish (R6), fused prep (R5), setprio (R9).
__global__ void __launch_bounds__(256) k_trees(
    const unsigned short* __restrict__ xc,   // [16384][512]
    const unsigned short* __restrict__ twb,  // [64*64][512]
    const float* __restrict__ tree_b,        // [64][63]
    const float* __restrict__ tree_temp,     // [64]
    const float* __restrict__ leaf,          // [64][64][10]
    const float* __restrict__ wbt,           // [16384][64]
    const unsigned char* __restrict__ flags, // [16384]
    unsigned short* __restrict__ part) {     // [16384][32][10] bf16
  __shared__ __align__(16) char smem[65536];
  char* A0 = smem;                                  // 128x64 bf16 = 16384
  char* B0 = smem + 16384;
  char* A1 = smem + 32768;
  char* B1 = smem + 49152;
  unsigned short* dh = (unsigned short*)smem;       // 2 planes x 128 x 66 f16 = 33792
  int lane = threadIdx.x & 63, wid = threadIdx.x >> 6;

  // XCD-chunked remap: id%8 -> XCD c; XCD (c&3, c>>2) owns x in
  // [(c&3)*8, +8), y in [(c>>2)*64, +64); j=id/8 walks x-fast within chunk.
  int idb = blockIdx.y * 32 + blockIdx.x;
  int cxcd = idb & 7, j = idb >> 3;
  int my_x = (cxcd & 3) * 8 + (j & 7);
  int my_y = (cxcd >> 2) * 64 + (j >> 3);
  int bm0 = my_y * 128;   // row tile
  int t0 = my_x * 2;      // tree pair

  int m = lane & 15, q = lane >> 4;
  int sub = lane >> 3, cpos = lane & 7;
  int wr = wid >> 1, wc = wid & 1;   // wave grid 2x2 over 128 rows x 128 cols
  int row_l = threadIdx.x & 127;
  int h = __builtin_amdgcn_readfirstlane((int)(threadIdx.x >> 7));  // wave-uniform half
  int grow = bm0 + row_l;

  f32x4 acc[4][4];
#pragma unroll
  for (int i = 0; i < 4; i++)
#pragma unroll
    for (int j2 = 0; j2 < 4; j2++) acc[i][j2] = f32x4{0.f, 0.f, 0.f, 0.f};

  const unsigned short* Ag = xc + (size_t)bm0 * 512;
  const unsigned short* Bg = twb + (size_t)t0 * 64 * 512;

  stage_trees(Ag, Bg, A0, B0, wid, sub, cpos);
  __syncthreads();  // prologue stage landed (only exposed drain)

#pragma unroll
  for (int ko = 0; ko < 8; ++ko) {
    char* As = (ko & 1) ? A1 : A0;
    char* Bs = (ko & 1) ? B1 : B0;
    if (ko < 7) {  // prefetch next K-tile BEFORE compute
      char* An = (ko & 1) ? A0 : A1;
      char* Bn = (ko & 1) ? B0 : B1;
      stage_trees(Ag + (ko + 1) * 64, Bg + (ko + 1) * 64, An, Bn, wid, sub, cpos);
    }
#pragma unroll
    for (int ks = 0; ks < 2; ++ks) {
      bf16x8 af[4], bfr[4];
#pragma unroll
      for (int mi = 0; mi < 4; mi++) af[mi] = frag_ld(As, wr * 64 + mi * 16 + m, ks * 4 + q);
#pragma unroll
      for (int ni = 0; ni < 4; ni++) bfr[ni] = frag_ld(Bs, wc * 64 + ni * 16 + m, ks * 4 + q);
#pragma unroll
      for (int mi = 0; mi < 4; mi++)
#pragma unroll
        for (int ni = 0; ni < 4; ni++)
          acc[mi][ni] = __builtin_amdgcn_mfma_f32_16x16x32_bf16(af[mi], bfr[ni], acc[mi][ni], 0, 0, 0);
    }
    __syncthreads();  // prefetch landed + this tile's readers done
  }
  // (final loop barrier above: GEMM tile readers done -> dh planes writable)

  // ---- epilogue: this wave owns tree t0+wc, rows wr*64..+63 ----
  uchar4 flv[4];
#pragma unroll
  for (int mi = 0; mi < 4; mi++)
    flv[mi] = *(const uchar4*)(flags + bm0 + wr * 64 + mi * 16 + q * 4);
  float2 wpair = *(const float2*)(wbt + grow * 64 + t0);  // prefetch weights

  {
    int t = t0 + wc;
    float nk2 = -1.44269504089f / tree_temp[t];  // -itemp*log2(e)
    float ncb[4];
#pragma unroll
    for (int ni = 0; ni < 4; ni++) {
      int node = ni * 16 + m;
      ncb[ni] = ((node < 63) ? tree_b[t * 63 + node] : 0.f) * nk2;
    }
#pragma unroll
    for (int mi = 0; mi < 4; mi++) {
      unsigned char fl[4] = {flv[mi].x, flv[mi].y, flv[mi].z, flv[mi].w};
#pragma unroll
      for (int ni = 0; ni < 4; ni++) {
        int node = ni * 16 + m;
        f32x4 a = acc[mi][ni];
#pragma unroll
        for (int r4 = 0; r4 < 4; r4++) {
          int row = wr * 64 + mi * 16 + q * 4 + r4;
          float e = exp2f(fmaf(a[r4], nk2, ncb[ni]));
          float sig = __builtin_amdgcn_rcpf(1.f + e);
          unsigned short hv = __half_as_ushort(__float2half(sig));
          hv = fl[r4] ? (unsigned short)0x3800 : hv;  // miss -> 0.5h
          dh[wc * HPLANE + row * HSTRIDE + node + 1] = hv;
        }
      }
    }
  }
  __syncthreads();

  // ---- routing + leaf for both trees (independent chains -> ILP) ----
  float pc[10];
#pragma unroll
  for (int c = 0; c < 10; c++) pc[c] = 0.f;

#pragma unroll
  for (int tt = 0; tt < 2; ++tt) {
    int t = t0 + tt;
    const unsigned short* dr = dh + tt * HPLANE + row_l * HSTRIDE;
    float R[16];
    {
      float d0 = __half2float(__ushort_as_half(dr[1]));
      R[0] = d0;
      R[1] = 1.f - d0;
    }
#pragma unroll
    for (int L = 1; L <= 3; ++L) {
      int half = 1 << L;
#pragma unroll
      for (int g = 0; g < half; g += 2) {
        float2 dd = __half22float2(*reinterpret_cast<const __half2*>(dr + half + g));
        float ra = R[g] * dd.x;
        R[g + half] = R[g] - ra;
        R[g] = ra;
        float rb = R[g + 1] * dd.y;
        R[g + 1 + half] = R[g + 1] - rb;
        R[g + 1] = rb;
      }
    }
#pragma unroll
    for (int p = 0; p < 16; p += 2) {
      float2 dd = __half22float2(*reinterpret_cast<const __half2*>(dr + 16 + p));
      float da = h ? (1.f - dd.x) : dd.x;
      float db = h ? (1.f - dd.y) : dd.y;
      R[p] *= da;
      R[p + 1] *= db;
    }
    float a10[10];
#pragma unroll
    for (int c = 0; c < 10; c++) a10[c] = 0.f;
    const float* Lf = leaf + (size_t)(t * 64 + 16 * h) * 10;
#pragma unroll
    for (int p = 0; p < 16; p += 2) {
      float2 dd = __half22float2(*reinterpret_cast<const __half2*>(dr + 32 + 16 * h + p));
      float rla = R[p] * dd.x, rra = R[p] - rla;
      float rlb = R[p + 1] * dd.y, rrb = R[p + 1] - rlb;
#pragma unroll
      for (int c = 0; c < 10; c++) {
        float s = fmaf(rla, Lf[p * 10 + c], a10[c]);
        s = fmaf(rra, Lf[320 + p * 10 + c], s);
        s = fmaf(rlb, Lf[p * 10 + 10 + c], s);
        a10[c] = fmaf(rrb, Lf[330 + p * 10 + c], s);
      }
    }
    float w = tt ? wpair.y : wpair.x;
#pragma unroll
    for (int c = 0; c < 10; c++) pc[c] = fmaf(w, a10[c], pc[c]);
  }

  // ---- combine halves in LDS, one non-atomic bf16 partial row per block ----
  __syncthreads();
  float* redbuf = reinterpret_cast<float*>(smem);  // 128 x 10 f32
  if (h == 1) {
#pragma unroll
    for (int c = 0; c < 10; c++) redbuf[row_l * 10 + c] = pc[c];
  }
  __syncthreads();
  if (h == 0) {
    unsigned short* po = part + ((size_t)grow * 32 + my_x) * 10;
    unsigned wdw[5];
#pragma unroll
    for (int k = 0; k < 5; k++) {
      unsigned lo = f2bf(pc[2 * k] + redbuf[row_l * 10 + 2 * k]);
      unsigned hi = f2bf(pc[2 * k + 1] + redbuf[row_l * 10 + 2 * k + 1]);
      wdw[k] = lo | (hi << 16);
    }
    unsigned* pu = reinterpret_cast<unsigned*>(po);
#pragma unroll
    for (int k = 0; k < 5; k++) pu[k] = wdw[k];
  }
}

// ---------------- final: reduce 32 bf16 slices + softmax ----------------
__global__ void __launch_bounds__(128) k_finish(const unsigned short* __restrict__ part,
                                               float* __restrict__ out) {
  int row = blockIdx.x * 128 + threadIdx.x;
  const uint4* pu = reinterpret_cast<const uint4*>(part + (size_t)row * 320);
  float v[10];
#pragma unroll
  for (int c = 0; c < 10; c++) v[c] = 0.f;
#pragma unroll
  for (int ch = 0; ch < 8; ++ch) {
    uint4 w0 = pu[ch * 5 + 0];
    uint4 w1 = pu[ch * 5 + 1];
    uint4 w2 = pu[ch * 5 + 2];
    uint4 w3 = pu[ch * 5 + 3];
    uint4 w4 = pu[ch * 5 + 4];
    unsigned dw[20] = {w0.x, w0.y, w0.z, w0.w, w1.x, w1.y, w1.z, w1.w,
                       w2.x, w2.y, w2.z, w2.w, w3.x, w3.y, w3.z, w3.w,
                       w4.x, w4.y, w4.z, w4.w};
#pragma unroll
    for (int d = 0; d < 20; d++) {
      int k = d % 5;
      v[2 * k] += bflo(dw[d]);
      v[2 * k + 1] += bfhi(dw[d]);
    }
  }
  float mx = -1e30f;
#pragma unroll
  for (int c = 0; c < 10; c++) mx = fmaxf(mx, v[c]);
  float sm = 0.f;
#pragma unroll
  for (int c = 0; c < 10; c++) {
    v[c] = __expf(v[c] - mx);
    sm += v[c];
  }
  float inv = 1.f / sm;
#pragma unroll
  for (int c = 0; c < 10; c++) out[row * 10 + c] = v[c] * inv;
}

extern "C" void kernel_launch(void* const* d_in, const int* in_sizes, int n_in,
                              void* d_out, int out_size, void* d_ws, size_t ws_size,
                              hipStream_t stream) {
  const float* x    = (const float*)d_in[0];
  const float* w1   = (const float*)d_in[1];
  const float* b1   = (const float*)d_in[2];
  const float* gam  = (const float*)d_in[3];
  const float* bet  = (const float*)d_in[4];
  const float* mu   = (const float*)d_in[5];
  const float* var  = (const float*)d_in[6];
  const float* w2   = (const float*)d_in[7];
  const float* b2   = (const float*)d_in[8];
  const float* tw   = (const float*)d_in[9];
  const float* tb   = (const float*)d_in[10];
  const float* temp = (const float*)d_in[11];
  const float* leaf = (const float*)d_in[12];
  const float* rw   = (const float*)d_in[13];
  float* out = (float*)d_out;

  char* ws = (char*)d_ws;
  unsigned short* xc  = (unsigned short*)(ws);             // 16,777,216 B
  unsigned short* twb = (unsigned short*)(ws + 16777216);  //  4,194,304 B
  unsigned short* w1t = (unsigned short*)(ws + 20971520);  //    131,072 B
  float* wbt  = (float*)(ws + 21102592);                   //  4,194,304 B
  unsigned char* flg = (unsigned char*)(ws + 25296896);    //     16,384 B
  unsigned short* part = (unsigned short*)(ws + 25362432); // 10,485,760 B

  k_prep<<<5376, 256, 0, stream>>>(tw, twb, w1, w1t, x, xc, flg);
  k_attn<<<512, 256, 0, stream>>>(xc, w1t, b1, gam, bet, mu, var,
                                  w2, b2, rw, wbt);
  dim3 g2(32, 128);
  k_trees<<<g2, 256, 0, stream>>>(xc, twb, tb, temp, leaf, wbt, flg, part);
  k_finish<<<128, 128, 0, stream>>>(part, out);
}